// Round 3
// baseline (4190.198 us; speedup 1.0000x reference)
//
#include <hip/hip_runtime.h>

// HeteroRGCNLayer: h_u = mean_uu(W_uu feat_u) + mean_vu(W_vu feat_v); h_v = mean_uv(W_uv feat_u)
// Strategy: linearity of mean => aggregate RAW feats per etype (segment sum + count),
// then fused GEMM: out = W * (agg/max(cnt,1)) + (cnt>0)*b   (summed over etypes per dst ntype).
//
// ws layout: agg[3][50000*128] f32 (76.8MB) | cnt[3][50000] i32 (600KB)  => 77.4MB total.

#define N_NODES 50000
#define E_EDGES 600000
#define D 128

static const size_t AGG_STRIDE = (size_t)N_NODES * D;          // floats per etype
static const size_t AGG_FLOATS = 3ull * AGG_STRIDE;            // 19.2M floats
static const size_t WS_BYTES   = AGG_FLOATS * 4ull + 3ull * N_NODES * 4ull;

__global__ __launch_bounds__(256) void count_kernel(
    const int* __restrict__ d0, const int* __restrict__ d1, const int* __restrict__ d2,
    int* __restrict__ cnt)
{
    int g = blockIdx.x * 256 + threadIdx.x;
    if (g >= 3 * E_EDGES) return;
    int seg, e;
    if (g < E_EDGES)          { seg = 0; e = g; }
    else if (g < 2 * E_EDGES) { seg = 1; e = g - E_EDGES; }
    else                      { seg = 2; e = g - 2 * E_EDGES; }
    const int* dp = (seg == 0) ? d0 : ((seg == 1) ? d1 : d2);
    atomicAdd(&cnt[seg * N_NODES + dp[e]], 1);
}

// 32 lanes per edge, float4 per lane. 8 edges per 256-thread block.
__global__ __launch_bounds__(256) void agg_kernel(
    const float* __restrict__ feat_u, const float* __restrict__ feat_v,
    const int* __restrict__ s0, const int* __restrict__ d0,   // uu: feat_u -> N_U
    const int* __restrict__ s1, const int* __restrict__ d1,   // vu: feat_v -> N_U
    const int* __restrict__ s2, const int* __restrict__ d2,   // uv: feat_u -> N_V
    float* __restrict__ agg)
{
    const int lane = threadIdx.x & 31;
    const int sub  = threadIdx.x >> 5;
    const int eg   = blockIdx.x * 8 + sub;          // [0, 1.8M)
    int seg, e;
    if (eg < E_EDGES)          { seg = 0; e = eg; }
    else if (eg < 2 * E_EDGES) { seg = 1; e = eg - E_EDGES; }
    else                       { seg = 2; e = eg - 2 * E_EDGES; }
    const int*   sp = (seg == 0) ? s0 : ((seg == 1) ? s1 : s2);
    const int*   dp = (seg == 0) ? d0 : ((seg == 1) ? d1 : d2);
    const float* f  = (seg == 1) ? feat_v : feat_u;
    const int src = sp[e];
    const int dst = dp[e];
    const float4 v = *(const float4*)&f[(size_t)src * D + lane * 4];
    float* a = agg + (size_t)seg * AGG_STRIDE + (size_t)dst * D + lane * 4;
    atomicAdd(a + 0, v.x);
    atomicAdd(a + 1, v.y);
    atomicAdd(a + 2, v.z);
    atomicAdd(a + 3, v.w);
}

// Fused GEMM + bias + mean-normalize. Block = 256 threads: o = tid&127 (output col),
// half = tid>>7 selects 32-row group; each thread accumulates 32 rows in registers.
// W (and W2) staged in LDS padded to 132 floats/row (16B-aligned, conflict-spread).
template <bool TWO>
__global__ __launch_bounds__(256, 1) void gemm_mean_kernel(
    const float* __restrict__ agg1, const int* __restrict__ cnt1,
    const float* __restrict__ W1g,  const float* __restrict__ b1,
    const float* __restrict__ agg2, const int* __restrict__ cnt2,
    const float* __restrict__ W2g,  const float* __restrict__ b2,
    float* __restrict__ out)
{
    __shared__ float Ws[TWO ? 2 : 1][128 * 132];
    const int t = threadIdx.x;

    // Stage W row-major [o][k] with +4 pad, float4 chunks (coalesced global, clean LDS writes)
    for (int i = t; i < (128 * 128) / 4; i += 256) {
        const int idx = i * 4;
        const int o = idx >> 7, k = idx & 127;
        *(float4*)&Ws[0][o * 132 + k] = *(const float4*)&W1g[idx];
        if (TWO) *(float4*)&Ws[1][o * 132 + k] = *(const float4*)&W2g[idx];
    }
    __syncthreads();

    const int o    = t & 127;
    const int half = __builtin_amdgcn_readfirstlane(t >> 7);  // wave-uniform -> scalar addrs
    const int row0 = blockIdx.x * 64 + half * 32;

    float acc1[32];
    float acc2[32];
#pragma unroll
    for (int r = 0; r < 32; ++r) { acc1[r] = 0.0f; if (TWO) acc2[r] = 0.0f; }

    for (int k = 0; k < 128; k += 4) {
        const float4 w1 = *(const float4*)&Ws[0][o * 132 + k];
        float4 w2;
        if (TWO) w2 = *(const float4*)&Ws[1][o * 132 + k];
#pragma unroll
        for (int r = 0; r < 32; ++r) {
            int i = row0 + r;
            if (i > N_NODES - 1) i = N_NODES - 1;   // clamp (tail block), store is guarded
            const float4 a1 = *(const float4*)&agg1[(size_t)i * D + k];
            acc1[r] += a1.x * w1.x + a1.y * w1.y + a1.z * w1.z + a1.w * w1.w;
            if (TWO) {
                const float4 a2 = *(const float4*)&agg2[(size_t)i * D + k];
                acc2[r] += a2.x * w2.x + a2.y * w2.y + a2.z * w2.z + a2.w * w2.w;
            }
        }
    }

    const float bo1 = b1[o];
    const float bo2 = TWO ? b2[o] : 0.0f;
#pragma unroll
    for (int r = 0; r < 32; ++r) {
        const int i = row0 + r;
        if (i < N_NODES) {
            const int c1 = cnt1[i];
            const float m1 = (float)(c1 > 1 ? c1 : 1);
            float v = acc1[r] / m1 + (c1 > 0 ? bo1 : 0.0f);
            if (TWO) {
                const int c2 = cnt2[i];
                const float m2 = (float)(c2 > 1 ? c2 : 1);
                v += acc2[r] / m2 + (c2 > 0 ? bo2 : 0.0f);
            }
            out[(size_t)i * D + o] = v;
        }
    }
}

extern "C" void kernel_launch(void* const* d_in, const int* in_sizes, int n_in,
                              void* d_out, int out_size, void* d_ws, size_t ws_size,
                              hipStream_t stream)
{
    const float* feat_u = (const float*)d_in[0];
    const float* feat_v = (const float*)d_in[1];
    const float* W_uu   = (const float*)d_in[2];
    const float* b_uu   = (const float*)d_in[3];
    const float* W_uv   = (const float*)d_in[4];
    const float* b_uv   = (const float*)d_in[5];
    const float* W_vu   = (const float*)d_in[6];
    const float* b_vu   = (const float*)d_in[7];
    const int* src_uu = (const int*)d_in[8];
    const int* dst_uu = (const int*)d_in[9];
    const int* src_uv = (const int*)d_in[10];
    const int* dst_uv = (const int*)d_in[11];
    const int* src_vu = (const int*)d_in[12];
    const int* dst_vu = (const int*)d_in[13];

    float* agg = (float*)d_ws;
    int*   cnt = (int*)((char*)d_ws + AGG_FLOATS * 4ull);
    float* out = (float*)d_out;

    // zero aggregates + counts (77.4MB)
    hipMemsetAsync(d_ws, 0, WS_BYTES, stream);

    // counts: seg0=uu, seg1=vu, seg2=uv
    {
        const int total = 3 * E_EDGES;
        count_kernel<<<(total + 255) / 256, 256, 0, stream>>>(dst_uu, dst_vu, dst_uv, cnt);
    }

    // feature aggregation (segment sums)
    {
        const int blocks = (3 * E_EDGES) / 8;   // 8 edges per block, divides exactly
        agg_kernel<<<blocks, 256, 0, stream>>>(feat_u, feat_v,
                                               src_uu, dst_uu,
                                               src_vu, dst_vu,
                                               src_uv, dst_uv,
                                               agg);
    }

    // h_u = W_uu*mean_uu + b_uu*ind + W_vu*mean_vu + b_vu*ind
    {
        const int blocks = (N_NODES + 63) / 64;  // 782
        gemm_mean_kernel<true><<<blocks, 256, 0, stream>>>(
            agg + 0 * AGG_STRIDE, cnt + 0 * N_NODES, W_uu, b_uu,
            agg + 1 * AGG_STRIDE, cnt + 1 * N_NODES, W_vu, b_vu,
            out);
    }
    // h_v = W_uv*mean_uv + b_uv*ind
    {
        const int blocks = (N_NODES + 63) / 64;
        gemm_mean_kernel<false><<<blocks, 256, 0, stream>>>(
            agg + 2 * AGG_STRIDE, cnt + 2 * N_NODES, W_uv, b_uv,
            nullptr, nullptr, nullptr, nullptr,
            out + (size_t)N_NODES * D);
    }
}

// Round 4
// 1403.766 us; speedup vs baseline: 2.9850x; 2.9850x over previous
//
#include <hip/hip_runtime.h>

// HeteroRGCNLayer — CSR pull-mode rewrite (round 4).
// mean(W x + b) = W mean(x) + 1[deg>0] b  =>  aggregate raw feats, GEMM once per etype.
// Pipeline: memset(cnt) -> count -> scan (offsets+cursor) -> scatter(edge_src) ->
//           pull (per-row gather+mean, NO float atomics) -> 3x gemm (+accumulate for h_u).
//
// ws: agg[3][50000][128] f32 (76.8MB) | cnt[150000] | offsets[150000] | cursor[150000]
//     | edge_src[1.8M]  => ~85.8MB

#define N_NODES 50000
#define E_EDGES 600000
#define D 128
#define NROWS (3 * N_NODES)   // 150000 CSR rows (seg0=uu->u, seg1=vu->u, seg2=uv->v)

static const size_t AGG_STRIDE = (size_t)N_NODES * D;
static const size_t AGG_BYTES  = 3ull * AGG_STRIDE * 4ull;   // 76,800,000

__global__ __launch_bounds__(256) void count_kernel(
    const int* __restrict__ d0, const int* __restrict__ d1, const int* __restrict__ d2,
    int* __restrict__ cnt)
{
    int g = blockIdx.x * 256 + threadIdx.x;
    if (g >= 3 * E_EDGES) return;
    int seg, e;
    if (g < E_EDGES)          { seg = 0; e = g; }
    else if (g < 2 * E_EDGES) { seg = 1; e = g - E_EDGES; }
    else                      { seg = 2; e = g - 2 * E_EDGES; }
    const int* dp = (seg == 0) ? d0 : ((seg == 1) ? d1 : d2);
    atomicAdd(&cnt[seg * N_NODES + dp[e]], 1);
}

// Single-block exclusive scan over 150000 counts -> offsets (and a mutable cursor copy).
__global__ __launch_bounds__(1024) void scan_kernel(
    const int* __restrict__ cnt, int* __restrict__ offsets, int* __restrict__ cursor)
{
    __shared__ int partial[1024];
    const int t = threadIdx.x;
    const int CHUNK = (NROWS + 1023) / 1024;   // 147
    const int base = t * CHUNK;
    int sum = 0;
    for (int i = 0; i < CHUNK; ++i) {
        const int idx = base + i;
        if (idx < NROWS) sum += cnt[idx];
    }
    partial[t] = sum;
    __syncthreads();
    for (int off = 1; off < 1024; off <<= 1) {   // Hillis-Steele inclusive scan
        int v = (t >= off) ? partial[t - off] : 0;
        __syncthreads();
        partial[t] += v;
        __syncthreads();
    }
    int run = (t == 0) ? 0 : partial[t - 1];     // exclusive prefix for this chunk
    for (int i = 0; i < CHUNK; ++i) {
        const int idx = base + i;
        if (idx < NROWS) {
            offsets[idx] = run;
            cursor[idx]  = run;
            run += cnt[idx];
        }
    }
}

__global__ __launch_bounds__(256) void scatter_kernel(
    const int* __restrict__ s0, const int* __restrict__ d0,
    const int* __restrict__ s1, const int* __restrict__ d1,
    const int* __restrict__ s2, const int* __restrict__ d2,
    int* __restrict__ cursor, int* __restrict__ edge_src)
{
    int g = blockIdx.x * 256 + threadIdx.x;
    if (g >= 3 * E_EDGES) return;
    int seg, e;
    if (g < E_EDGES)          { seg = 0; e = g; }
    else if (g < 2 * E_EDGES) { seg = 1; e = g - E_EDGES; }
    else                      { seg = 2; e = g - 2 * E_EDGES; }
    const int* sp = (seg == 0) ? s0 : ((seg == 1) ? s1 : s2);
    const int* dp = (seg == 0) ? d0 : ((seg == 1) ? d1 : d2);
    const int pos = atomicAdd(&cursor[seg * N_NODES + dp[e]], 1);
    edge_src[pos] = sp[e];
}

// One 32-lane group per CSR row: batch-load edge ids, shfl-broadcast, gather 512B
// coalesced feat rows, register-accumulate, write MEAN once. No float atomics.
__global__ __launch_bounds__(256) void pull_kernel(
    const float* __restrict__ feat_u, const float* __restrict__ feat_v,
    const int* __restrict__ offsets, const int* __restrict__ cnt,
    const int* __restrict__ edge_src, float* __restrict__ agg)
{
    const int lane = threadIdx.x & 31;
    const int grp  = threadIdx.x >> 5;
    const int row  = blockIdx.x * 8 + grp;
    if (row >= NROWS) return;
    const float* f = (row >= N_NODES && row < 2 * N_NODES) ? feat_v : feat_u;
    const int start = offsets[row];
    const int deg   = cnt[row];
    float4 acc = make_float4(0.f, 0.f, 0.f, 0.f);
    for (int base = 0; base < deg; base += 32) {
        int id = 0;
        if (base + lane < deg) id = edge_src[start + base + lane];
        const int m = (deg - base < 32) ? (deg - base) : 32;
        int e = 0;
        for (; e + 1 < m; e += 2) {   // 2-deep load pipelining
            const int src0 = __shfl(id, e, 32);
            const int src1 = __shfl(id, e + 1, 32);
            const float4 v0 = *(const float4*)&f[(size_t)src0 * D + lane * 4];
            const float4 v1 = *(const float4*)&f[(size_t)src1 * D + lane * 4];
            acc.x += v0.x; acc.y += v0.y; acc.z += v0.z; acc.w += v0.w;
            acc.x += v1.x; acc.y += v1.y; acc.z += v1.z; acc.w += v1.w;
        }
        if (e < m) {
            const int src0 = __shfl(id, e, 32);
            const float4 v0 = *(const float4*)&f[(size_t)src0 * D + lane * 4];
            acc.x += v0.x; acc.y += v0.y; acc.z += v0.z; acc.w += v0.w;
        }
    }
    const float inv = (deg > 0) ? (1.0f / (float)deg) : 0.0f;
    acc.x *= inv; acc.y *= inv; acc.z *= inv; acc.w *= inv;
    *(float4*)&agg[(size_t)row * D + lane * 4] = acc;
}

// out[i][o] (+)= sum_k mean[i][k] * W[o][k] + (cnt[i]>0 ? b[o] : 0)
// Single W in LDS (67.5KB -> 2 blocks/CU). ADD accumulates into out (2nd etype of h_u).
template <bool ADD>
__global__ __launch_bounds__(256) void gemm_kernel(
    const float* __restrict__ aggm, const int* __restrict__ cntp,
    const float* __restrict__ Wg,   const float* __restrict__ bg,
    float* __restrict__ out)
{
    __shared__ float Ws[128 * 132];
    const int t = threadIdx.x;
    for (int i = t; i < (128 * 128) / 4; i += 256) {
        const int idx = i * 4;
        const int o = idx >> 7, k = idx & 127;
        *(float4*)&Ws[o * 132 + k] = *(const float4*)&Wg[idx];
    }
    __syncthreads();

    const int o    = t & 127;
    const int half = __builtin_amdgcn_readfirstlane(t >> 7);
    const int row0 = blockIdx.x * 64 + half * 32;

    float acc[32];
#pragma unroll
    for (int r = 0; r < 32; ++r) acc[r] = 0.0f;

    for (int k = 0; k < 128; k += 4) {
        const float4 w = *(const float4*)&Ws[o * 132 + k];
#pragma unroll
        for (int r = 0; r < 32; ++r) {
            int i = row0 + r;
            if (i > N_NODES - 1) i = N_NODES - 1;   // clamp; store is guarded
            const float4 a = *(const float4*)&aggm[(size_t)i * D + k];
            acc[r] += a.x * w.x + a.y * w.y + a.z * w.z + a.w * w.w;
        }
    }

    const float bo = bg[o];
#pragma unroll
    for (int r = 0; r < 32; ++r) {
        const int i = row0 + r;
        if (i < N_NODES) {
            const int c = cntp[i];
            float v = acc[r] + (c > 0 ? bo : 0.0f);
            if (ADD) v += out[(size_t)i * D + o];
            out[(size_t)i * D + o] = v;
        }
    }
}

extern "C" void kernel_launch(void* const* d_in, const int* in_sizes, int n_in,
                              void* d_out, int out_size, void* d_ws, size_t ws_size,
                              hipStream_t stream)
{
    const float* feat_u = (const float*)d_in[0];
    const float* feat_v = (const float*)d_in[1];
    const float* W_uu   = (const float*)d_in[2];
    const float* b_uu   = (const float*)d_in[3];
    const float* W_uv   = (const float*)d_in[4];
    const float* b_uv   = (const float*)d_in[5];
    const float* W_vu   = (const float*)d_in[6];
    const float* b_vu   = (const float*)d_in[7];
    const int* src_uu = (const int*)d_in[8];
    const int* dst_uu = (const int*)d_in[9];
    const int* src_uv = (const int*)d_in[10];
    const int* dst_uv = (const int*)d_in[11];
    const int* src_vu = (const int*)d_in[12];
    const int* dst_vu = (const int*)d_in[13];

    char* ws = (char*)d_ws;
    float* agg     = (float*)ws;                                   // 76.8MB
    int*   cnt     = (int*)(ws + AGG_BYTES);                       // 600KB
    int*   offsets = (int*)(ws + AGG_BYTES +     600000ull);       // 600KB
    int*   cursor  = (int*)(ws + AGG_BYTES + 2ull * 600000ull);    // 600KB
    int*   edge_src= (int*)(ws + AGG_BYTES + 3ull * 600000ull);    // 7.2MB
    float* out = (float*)d_out;

    hipMemsetAsync(cnt, 0, (size_t)NROWS * 4, stream);

    const int eblocks = (3 * E_EDGES + 255) / 256;
    count_kernel<<<eblocks, 256, 0, stream>>>(dst_uu, dst_vu, dst_uv, cnt);
    scan_kernel<<<1, 1024, 0, stream>>>(cnt, offsets, cursor);
    scatter_kernel<<<eblocks, 256, 0, stream>>>(src_uu, dst_uu,
                                                src_vu, dst_vu,
                                                src_uv, dst_uv,
                                                cursor, edge_src);
    pull_kernel<<<(NROWS + 7) / 8, 256, 0, stream>>>(feat_u, feat_v,
                                                     offsets, cnt, edge_src, agg);

    const int gblocks = (N_NODES + 63) / 64;   // 782
    gemm_kernel<false><<<gblocks, 256, 0, stream>>>(
        agg + 0 * AGG_STRIDE, cnt + 0 * N_NODES, W_uu, b_uu, out);
    gemm_kernel<true><<<gblocks, 256, 0, stream>>>(
        agg + 1 * AGG_STRIDE, cnt + 1 * N_NODES, W_vu, b_vu, out);
    gemm_kernel<false><<<gblocks, 256, 0, stream>>>(
        agg + 2 * AGG_STRIDE, cnt + 2 * N_NODES, W_uv, b_uv,
        out + (size_t)N_NODES * D);
}

// Round 6
// 1119.106 us; speedup vs baseline: 3.7442x; 1.2544x over previous
//
#include <hip/hip_runtime.h>

// HeteroRGCNLayer — round 5: Wh-first + atomic-offset CSR (no serial scan).
// Reference order preserved: Wh = feat @ W^T + b  (dense GEMM, bias folded),
// then CSR pull: out_u[i] = mean_uu(Wh_uu) + mean_vu(Wh_vu); out_v = mean_uv(Wh_uv).
// deg==0 segments contribute 0 (DGL mean semantics).
//
// ws: Wh[3][50000][128] f32 (76.8MB) | cnt[150000] | total | offsets[150000]
//     | cursor[150000] | edge_src[1.8M]  => ~85.8MB (same as round-4 proven size)

#define N_NODES 50000
#define E_EDGES 600000
#define D 128
#define NROWS (3 * N_NODES)   // seg0=uu->u, seg1=vu->u, seg2=uv->v

static const size_t WH_STRIDE = (size_t)N_NODES * D;           // floats per etype
static const size_t WH_BYTES  = 3ull * WH_STRIDE * 4ull;       // 76,800,000
static const size_t OFF_CNT   = WH_BYTES;                      // 150000 ints
static const size_t OFF_TOT   = OFF_CNT + 600000ull;           // 1 int (+pad)
static const size_t OFF_OFFS  = OFF_TOT + 64ull;               // 150000 ints
static const size_t OFF_CUR   = OFF_OFFS + 600000ull;          // 150000 ints
static const size_t OFF_ESRC  = OFF_CUR + 600000ull;           // 1.8M ints

__global__ __launch_bounds__(256) void count_kernel(
    const int* __restrict__ d0, const int* __restrict__ d1, const int* __restrict__ d2,
    int* __restrict__ cnt)
{
    int g = blockIdx.x * 256 + threadIdx.x;
    if (g >= 3 * E_EDGES) return;
    int seg, e;
    if (g < E_EDGES)          { seg = 0; e = g; }
    else if (g < 2 * E_EDGES) { seg = 1; e = g - E_EDGES; }
    else                      { seg = 2; e = g - 2 * E_EDGES; }
    const int* dp = (seg == 0) ? d0 : ((seg == 1) ? d1 : d2);
    atomicAdd(&cnt[seg * N_NODES + dp[e]], 1);
}

// Decoupled unordered "scan": wave-level shfl prefix + one atomicAdd per wave.
// Row placement order is nondeterministic but CSR only needs disjoint ranges.
__global__ __launch_bounds__(256) void offsets_kernel(
    const int* __restrict__ cnt, int* __restrict__ offsets,
    int* __restrict__ cursor, int* __restrict__ total)
{
    const int g = blockIdx.x * 256 + threadIdx.x;
    const int lane = threadIdx.x & 63;
    const int c = (g < NROWS) ? cnt[g] : 0;
    int x = c;                                   // inclusive wave prefix
#pragma unroll
    for (int off = 1; off < 64; off <<= 1) {
        int v = __shfl_up(x, off, 64);
        if (lane >= off) x += v;
    }
    const int wtot = __shfl(x, 63, 64);
    int base = 0;
    if (lane == 0) base = atomicAdd(total, wtot);
    base = __shfl(base, 0, 64);
    const int o = base + x - c;                  // exclusive within wave
    if (g < NROWS) { offsets[g] = o; cursor[g] = o; }
}

__global__ __launch_bounds__(256) void scatter_kernel(
    const int* __restrict__ s0, const int* __restrict__ d0,
    const int* __restrict__ s1, const int* __restrict__ d1,
    const int* __restrict__ s2, const int* __restrict__ d2,
    int* __restrict__ cursor, int* __restrict__ edge_src)
{
    int g = blockIdx.x * 256 + threadIdx.x;
    if (g >= 3 * E_EDGES) return;
    int seg, e;
    if (g < E_EDGES)          { seg = 0; e = g; }
    else if (g < 2 * E_EDGES) { seg = 1; e = g - E_EDGES; }
    else                      { seg = 2; e = g - 2 * E_EDGES; }
    const int* sp = (seg == 0) ? s0 : ((seg == 1) ? s1 : s2);
    const int* dp = (seg == 0) ? d0 : ((seg == 1) ? d1 : d2);
    const int pos = atomicAdd(&cursor[seg * N_NODES + dp[e]], 1);
    edge_src[pos] = sp[e];
}

// Wh[i][o] = sum_k feat[i][k] * W[o][k] + b[o]   (bias folded; mean is linear)
__global__ __launch_bounds__(256) void gemm_kernel(
    const float* __restrict__ feat, const float* __restrict__ Wg,
    const float* __restrict__ bg,   float* __restrict__ Wh)
{
    __shared__ float Ws[128 * 132];
    const int t = threadIdx.x;
    for (int i = t; i < (128 * 128) / 4; i += 256) {
        const int idx = i * 4;
        const int o = idx >> 7, k = idx & 127;
        *(float4*)&Ws[o * 132 + k] = *(const float4*)&Wg[idx];
    }
    __syncthreads();

    const int o    = t & 127;
    const int half = __builtin_amdgcn_readfirstlane(t >> 7);
    const int row0 = blockIdx.x * 64 + half * 32;

    float acc[32];
#pragma unroll
    for (int r = 0; r < 32; ++r) acc[r] = 0.0f;

    for (int k = 0; k < 128; k += 4) {
        const float4 w = *(const float4*)&Ws[o * 132 + k];
#pragma unroll
        for (int r = 0; r < 32; ++r) {
            int i = row0 + r;
            if (i > N_NODES - 1) i = N_NODES - 1;   // clamp; store guarded
            const float4 a = *(const float4*)&feat[(size_t)i * D + k];
            acc[r] += a.x * w.x + a.y * w.y + a.z * w.z + a.w * w.w;
        }
    }

    const float bo = bg[o];
#pragma unroll
    for (int r = 0; r < 32; ++r) {
        const int i = row0 + r;
        if (i < N_NODES) Wh[(size_t)i * D + o] = acc[r] + bo;
    }
}

// 32-lane group segment-mean gather over one CSR row.
__device__ __forceinline__ float4 seg_mean(
    const float* __restrict__ tab, const int* __restrict__ edge_src,
    int start, int deg, int lane)
{
    float4 acc = make_float4(0.f, 0.f, 0.f, 0.f);
    for (int base = 0; base < deg; base += 32) {
        int id = 0;
        if (base + lane < deg) id = edge_src[start + base + lane];
        const int m = (deg - base < 32) ? (deg - base) : 32;
        int e = 0;
        for (; e + 1 < m; e += 2) {   // 2-deep load pipelining
            const int s0 = __shfl(id, e, 32);
            const int s1 = __shfl(id, e + 1, 32);
            const float4 v0 = *(const float4*)&tab[(size_t)s0 * D + lane * 4];
            const float4 v1 = *(const float4*)&tab[(size_t)s1 * D + lane * 4];
            acc.x += v0.x + v1.x; acc.y += v0.y + v1.y;
            acc.z += v0.z + v1.z; acc.w += v0.w + v1.w;
        }
        if (e < m) {
            const int s0 = __shfl(id, e, 32);
            const float4 v0 = *(const float4*)&tab[(size_t)s0 * D + lane * 4];
            acc.x += v0.x; acc.y += v0.y; acc.z += v0.z; acc.w += v0.w;
        }
    }
    if (deg > 0) {
        const float inv = 1.0f / (float)deg;
        acc.x *= inv; acc.y *= inv; acc.z *= inv; acc.w *= inv;
    }
    return acc;   // deg==0 -> zeros (DGL mean semantics)
}

// rows [0,50000): out_u = mean(seg0 over Wh_uu) + mean(seg1 over Wh_vu)
// rows [50000,100000): out_v = mean(seg2 over Wh_uv)
__global__ __launch_bounds__(256) void pull_kernel(
    const float* __restrict__ Wh_uu, const float* __restrict__ Wh_vu,
    const float* __restrict__ Wh_uv,
    const int* __restrict__ offsets, const int* __restrict__ cnt,
    const int* __restrict__ edge_src, float* __restrict__ out)
{
    const int lane = threadIdx.x & 31;
    const int grp  = threadIdx.x >> 5;
    const int row  = blockIdx.x * 8 + grp;    // [0, 100000), grid exact
    if (row < N_NODES) {
        const float4 a = seg_mean(Wh_uu, edge_src, offsets[row], cnt[row], lane);
        const float4 b = seg_mean(Wh_vu, edge_src,
                                  offsets[N_NODES + row], cnt[N_NODES + row], lane);
        const float4 r = make_float4(a.x + b.x, a.y + b.y, a.z + b.z, a.w + b.w);
        *(float4*)&out[(size_t)row * D + lane * 4] = r;
    } else {
        const int rr = row - N_NODES;
        const float4 a = seg_mean(Wh_uv, edge_src,
                                  offsets[2 * N_NODES + rr], cnt[2 * N_NODES + rr], lane);
        *(float4*)&out[((size_t)N_NODES + rr) * D + lane * 4] = a;
    }
}

extern "C" void kernel_launch(void* const* d_in, const int* in_sizes, int n_in,
                              void* d_out, int out_size, void* d_ws, size_t ws_size,
                              hipStream_t stream)
{
    const float* feat_u = (const float*)d_in[0];
    const float* feat_v = (const float*)d_in[1];
    const float* W_uu   = (const float*)d_in[2];
    const float* b_uu   = (const float*)d_in[3];
    const float* W_uv   = (const float*)d_in[4];
    const float* b_uv   = (const float*)d_in[5];
    const float* W_vu   = (const float*)d_in[6];
    const float* b_vu   = (const float*)d_in[7];
    const int* src_uu = (const int*)d_in[8];
    const int* dst_uu = (const int*)d_in[9];
    const int* src_uv = (const int*)d_in[10];
    const int* dst_uv = (const int*)d_in[11];
    const int* src_vu = (const int*)d_in[12];
    const int* dst_vu = (const int*)d_in[13];

    char* ws = (char*)d_ws;
    float* Wh      = (float*)ws;
    int*   cnt     = (int*)(ws + OFF_CNT);
    int*   total   = (int*)(ws + OFF_TOT);
    int*   offsets = (int*)(ws + OFF_OFFS);
    int*   cursor  = (int*)(ws + OFF_CUR);
    int*   edge_src= (int*)(ws + OFF_ESRC);
    float* out = (float*)d_out;

    // zero counts + total cursor base
    hipMemsetAsync(cnt, 0, 600064ull, stream);

    const int eblocks = (3 * E_EDGES + 255) / 256;
    count_kernel<<<eblocks, 256, 0, stream>>>(dst_uu, dst_vu, dst_uv, cnt);
    offsets_kernel<<<(NROWS + 255) / 256, 256, 0, stream>>>(cnt, offsets, cursor, total);
    scatter_kernel<<<eblocks, 256, 0, stream>>>(src_uu, dst_uu,
                                                src_vu, dst_vu,
                                                src_uv, dst_uv,
                                                cursor, edge_src);

    const int gblocks = (N_NODES + 63) / 64;   // 782
    gemm_kernel<<<gblocks, 256, 0, stream>>>(feat_u, W_uu, b_uu, Wh + 0 * WH_STRIDE);
    gemm_kernel<<<gblocks, 256, 0, stream>>>(feat_v, W_vu, b_vu, Wh + 1 * WH_STRIDE);
    gemm_kernel<<<gblocks, 256, 0, stream>>>(feat_u, W_uv, b_uv, Wh + 2 * WH_STRIDE);

    pull_kernel<<<(2 * N_NODES) / 8, 256, 0, stream>>>(
        Wh + 0 * WH_STRIDE, Wh + 1 * WH_STRIDE, Wh + 2 * WH_STRIDE,
        offsets, cnt, edge_src, out);
}

// Round 7
// 549.834 us; speedup vs baseline: 7.6208x; 2.0354x over previous
//
#include <hip/hip_runtime.h>

// HeteroRGCNLayer — round 7: fused register-blocked SGEMM (gemm3) + Wh-first CSR pull.
// Pipeline: memset(cnt) -> count -> offsets (wave-prefix atomic) -> scatter ->
//           gemm3 (all 3 etypes, one launch) -> pull (segment-mean gather -> out).
//
// ws: Wh[3][50000][128] f32 (76.8MB) | cnt[150000] | total | offsets[150000]
//     | cursor[150000] | edge_src[1.8M]  => ~85.8MB

#define N_NODES 50000
#define E_EDGES 600000
#define D 128
#define NROWS (3 * N_NODES)   // seg0=uu->u, seg1=vu->u, seg2=uv->v

#define RT 64                 // rows per GEMM tile
#define KC 16                 // k-chunk
#define NT ((N_NODES + RT - 1) / RT)   // 782 tiles per segment

static const size_t WH_STRIDE = (size_t)N_NODES * D;
static const size_t WH_BYTES  = 3ull * WH_STRIDE * 4ull;       // 76,800,000
static const size_t OFF_CNT   = WH_BYTES;
static const size_t OFF_TOT   = OFF_CNT + 600000ull;
static const size_t OFF_OFFS  = OFF_TOT + 64ull;
static const size_t OFF_CUR   = OFF_OFFS + 600000ull;
static const size_t OFF_ESRC  = OFF_CUR + 600000ull;

__global__ __launch_bounds__(256) void count_kernel(
    const int* __restrict__ d0, const int* __restrict__ d1, const int* __restrict__ d2,
    int* __restrict__ cnt)
{
    int g = blockIdx.x * 256 + threadIdx.x;
    if (g >= 3 * E_EDGES) return;
    int seg, e;
    if (g < E_EDGES)          { seg = 0; e = g; }
    else if (g < 2 * E_EDGES) { seg = 1; e = g - E_EDGES; }
    else                      { seg = 2; e = g - 2 * E_EDGES; }
    const int* dp = (seg == 0) ? d0 : ((seg == 1) ? d1 : d2);
    atomicAdd(&cnt[seg * N_NODES + dp[e]], 1);
}

// Unordered CSR offsets: wave shfl prefix + one atomicAdd per wave (disjoint ranges suffice).
__global__ __launch_bounds__(256) void offsets_kernel(
    const int* __restrict__ cnt, int* __restrict__ offsets,
    int* __restrict__ cursor, int* __restrict__ total)
{
    const int g = blockIdx.x * 256 + threadIdx.x;
    const int lane = threadIdx.x & 63;
    const int c = (g < NROWS) ? cnt[g] : 0;
    int x = c;
#pragma unroll
    for (int off = 1; off < 64; off <<= 1) {
        int v = __shfl_up(x, off, 64);
        if (lane >= off) x += v;
    }
    const int wtot = __shfl(x, 63, 64);
    int base = 0;
    if (lane == 0) base = atomicAdd(total, wtot);
    base = __shfl(base, 0, 64);
    const int o = base + x - c;
    if (g < NROWS) { offsets[g] = o; cursor[g] = o; }
}

__global__ __launch_bounds__(256) void scatter_kernel(
    const int* __restrict__ s0, const int* __restrict__ d0,
    const int* __restrict__ s1, const int* __restrict__ d1,
    const int* __restrict__ s2, const int* __restrict__ d2,
    int* __restrict__ cursor, int* __restrict__ edge_src)
{
    int g = blockIdx.x * 256 + threadIdx.x;
    if (g >= 3 * E_EDGES) return;
    int seg, e;
    if (g < E_EDGES)          { seg = 0; e = g; }
    else if (g < 2 * E_EDGES) { seg = 1; e = g - E_EDGES; }
    else                      { seg = 2; e = g - 2 * E_EDGES; }
    const int* sp = (seg == 0) ? s0 : ((seg == 1) ? s1 : s2);
    const int* dp = (seg == 0) ? d0 : ((seg == 1) ? d1 : d2);
    const int pos = atomicAdd(&cursor[seg * N_NODES + dp[e]], 1);
    edge_src[pos] = sp[e];
}

// Fused 3-etype SGEMM: Wh[seg][i][o] = sum_k feat_seg[i][k]*W_seg[o][k] + b_seg[o].
// Block: 256 thr = 16(tx) x 16(ty); tile RT=64 rows x 128 cols; micro-tile 4x8 per thread.
// LDS: As[kk][row] (broadcast reads), Bs[kk][col]+pad (b128 reads). 12.25KB -> high occupancy.
__global__ __launch_bounds__(256) void gemm3_kernel(
    const float* __restrict__ feat_u, const float* __restrict__ feat_v,
    const float* __restrict__ W_uu, const float* __restrict__ b_uu,
    const float* __restrict__ W_vu, const float* __restrict__ b_vu,
    const float* __restrict__ W_uv, const float* __restrict__ b_uv,
    float* __restrict__ Wh)
{
    __shared__ float As[KC][RT];      // 4KB
    __shared__ float Bs[KC][132];     // 8.45KB (pad 132 words)

    const int bx   = blockIdx.x;
    const int seg  = bx / NT;
    const int tile = bx - seg * NT;
    const float* feat = (seg == 1) ? feat_v : feat_u;
    const float* W    = (seg == 0) ? W_uu : ((seg == 1) ? W_vu : W_uv);
    const float* bb   = (seg == 0) ? b_uu : ((seg == 1) ? b_vu : b_uv);
    float* WhS = Wh + (size_t)seg * WH_STRIDE;

    const int t  = threadIdx.x;
    const int tx = t & 15;
    const int ty = t >> 4;
    const int row0 = tile * RT;

    // staging indices
    const int ar = t >> 2;            // 0..63 row within tile
    const int ak = (t & 3) * 4;       // 0,4,8,12
    int grow = row0 + ar; if (grow > N_NODES - 1) grow = N_NODES - 1;
    const int wcol = t & 127;         // 0..127
    const int wkh  = (t >> 7) * 8;    // 0 or 8

    float acc[4][8];
#pragma unroll
    for (int r = 0; r < 4; ++r)
#pragma unroll
        for (int c = 0; c < 8; ++c) acc[r][c] = 0.0f;

    for (int kc = 0; kc < D; kc += KC) {
        // stage A chunk: 64 rows x 16 k (coalesced 64B-line loads)
        {
            const float4 v = *(const float4*)&feat[(size_t)grow * D + kc + ak];
            As[ak + 0][ar] = v.x; As[ak + 1][ar] = v.y;
            As[ak + 2][ar] = v.z; As[ak + 3][ar] = v.w;
        }
        // stage B chunk: 128 cols x 16 k (W row-major [o][k], contiguous along k)
        {
            const float4 v0 = *(const float4*)&W[(size_t)wcol * D + kc + wkh + 0];
            const float4 v1 = *(const float4*)&W[(size_t)wcol * D + kc + wkh + 4];
            Bs[wkh + 0][wcol] = v0.x; Bs[wkh + 1][wcol] = v0.y;
            Bs[wkh + 2][wcol] = v0.z; Bs[wkh + 3][wcol] = v0.w;
            Bs[wkh + 4][wcol] = v1.x; Bs[wkh + 5][wcol] = v1.y;
            Bs[wkh + 6][wcol] = v1.z; Bs[wkh + 7][wcol] = v1.w;
        }
        __syncthreads();

#pragma unroll
        for (int kk = 0; kk < KC; ++kk) {
            const float4 av = *(const float4*)&As[kk][ty * 4];
            const float4 b0 = *(const float4*)&Bs[kk][tx * 8];
            const float4 b1 = *(const float4*)&Bs[kk][tx * 8 + 4];
            const float ae[4] = {av.x, av.y, av.z, av.w};
            const float be[8] = {b0.x, b0.y, b0.z, b0.w, b1.x, b1.y, b1.z, b1.w};
#pragma unroll
            for (int r = 0; r < 4; ++r)
#pragma unroll
                for (int c = 0; c < 8; ++c)
                    acc[r][c] += ae[r] * be[c];
        }
        __syncthreads();
    }

    // epilogue: bias + store (rows guarded)
    const float4 bv0 = *(const float4*)&bb[tx * 8];
    const float4 bv1 = *(const float4*)&bb[tx * 8 + 4];
#pragma unroll
    for (int r = 0; r < 4; ++r) {
        const int row = row0 + ty * 4 + r;
        if (row < N_NODES) {
            float4 o0, o1;
            o0.x = acc[r][0] + bv0.x; o0.y = acc[r][1] + bv0.y;
            o0.z = acc[r][2] + bv0.z; o0.w = acc[r][3] + bv0.w;
            o1.x = acc[r][4] + bv1.x; o1.y = acc[r][5] + bv1.y;
            o1.z = acc[r][6] + bv1.z; o1.w = acc[r][7] + bv1.w;
            *(float4*)&WhS[(size_t)row * D + tx * 8]     = o0;
            *(float4*)&WhS[(size_t)row * D + tx * 8 + 4] = o1;
        }
    }
}

// 32-lane group segment-mean gather over one CSR row.
__device__ __forceinline__ float4 seg_mean(
    const float* __restrict__ tab, const int* __restrict__ edge_src,
    int start, int deg, int lane)
{
    float4 acc = make_float4(0.f, 0.f, 0.f, 0.f);
    for (int base = 0; base < deg; base += 32) {
        int id = 0;
        if (base + lane < deg) id = edge_src[start + base + lane];
        const int m = (deg - base < 32) ? (deg - base) : 32;
        int e = 0;
        for (; e + 1 < m; e += 2) {
            const int s0 = __shfl(id, e, 32);
            const int s1 = __shfl(id, e + 1, 32);
            const float4 v0 = *(const float4*)&tab[(size_t)s0 * D + lane * 4];
            const float4 v1 = *(const float4*)&tab[(size_t)s1 * D + lane * 4];
            acc.x += v0.x + v1.x; acc.y += v0.y + v1.y;
            acc.z += v0.z + v1.z; acc.w += v0.w + v1.w;
        }
        if (e < m) {
            const int s0 = __shfl(id, e, 32);
            const float4 v0 = *(const float4*)&tab[(size_t)s0 * D + lane * 4];
            acc.x += v0.x; acc.y += v0.y; acc.z += v0.z; acc.w += v0.w;
        }
    }
    if (deg > 0) {
        const float inv = 1.0f / (float)deg;
        acc.x *= inv; acc.y *= inv; acc.z *= inv; acc.w *= inv;
    }
    return acc;
}

__global__ __launch_bounds__(256) void pull_kernel(
    const float* __restrict__ Wh_uu, const float* __restrict__ Wh_vu,
    const float* __restrict__ Wh_uv,
    const int* __restrict__ offsets, const int* __restrict__ cnt,
    const int* __restrict__ edge_src, float* __restrict__ out)
{
    const int lane = threadIdx.x & 31;
    const int grp  = threadIdx.x >> 5;
    const int row  = blockIdx.x * 8 + grp;
    if (row < N_NODES) {
        const float4 a = seg_mean(Wh_uu, edge_src, offsets[row], cnt[row], lane);
        const float4 b = seg_mean(Wh_vu, edge_src,
                                  offsets[N_NODES + row], cnt[N_NODES + row], lane);
        const float4 r = make_float4(a.x + b.x, a.y + b.y, a.z + b.z, a.w + b.w);
        *(float4*)&out[(size_t)row * D + lane * 4] = r;
    } else {
        const int rr = row - N_NODES;
        const float4 a = seg_mean(Wh_uv, edge_src,
                                  offsets[2 * N_NODES + rr], cnt[2 * N_NODES + rr], lane);
        *(float4*)&out[((size_t)N_NODES + rr) * D + lane * 4] = a;
    }
}

extern "C" void kernel_launch(void* const* d_in, const int* in_sizes, int n_in,
                              void* d_out, int out_size, void* d_ws, size_t ws_size,
                              hipStream_t stream)
{
    const float* feat_u = (const float*)d_in[0];
    const float* feat_v = (const float*)d_in[1];
    const float* W_uu   = (const float*)d_in[2];
    const float* b_uu   = (const float*)d_in[3];
    const float* W_uv   = (const float*)d_in[4];
    const float* b_uv   = (const float*)d_in[5];
    const float* W_vu   = (const float*)d_in[6];
    const float* b_vu   = (const float*)d_in[7];
    const int* src_uu = (const int*)d_in[8];
    const int* dst_uu = (const int*)d_in[9];
    const int* src_uv = (const int*)d_in[10];
    const int* dst_uv = (const int*)d_in[11];
    const int* src_vu = (const int*)d_in[12];
    const int* dst_vu = (const int*)d_in[13];

    char* ws = (char*)d_ws;
    float* Wh      = (float*)ws;
    int*   cnt     = (int*)(ws + OFF_CNT);
    int*   total   = (int*)(ws + OFF_TOT);
    int*   offsets = (int*)(ws + OFF_OFFS);
    int*   cursor  = (int*)(ws + OFF_CUR);
    int*   edge_src= (int*)(ws + OFF_ESRC);
    float* out = (float*)d_out;

    hipMemsetAsync(cnt, 0, 600064ull, stream);

    const int eblocks = (3 * E_EDGES + 255) / 256;
    count_kernel<<<eblocks, 256, 0, stream>>>(dst_uu, dst_vu, dst_uv, cnt);
    offsets_kernel<<<(NROWS + 255) / 256, 256, 0, stream>>>(cnt, offsets, cursor, total);
    scatter_kernel<<<eblocks, 256, 0, stream>>>(src_uu, dst_uu,
                                                src_vu, dst_vu,
                                                src_uv, dst_uv,
                                                cursor, edge_src);

    gemm3_kernel<<<3 * NT, 256, 0, stream>>>(feat_u, feat_v,
                                             W_uu, b_uu, W_vu, b_vu, W_uv, b_uv, Wh);

    pull_kernel<<<(2 * N_NODES) / 8, 256, 0, stream>>>(
        Wh + 0 * WH_STRIDE, Wh + 1 * WH_STRIDE, Wh + 2 * WH_STRIDE,
        offsets, cnt, edge_src, out);
}

// Round 10
// 501.627 us; speedup vs baseline: 8.3532x; 1.0961x over previous
//
#include <hip/hip_runtime.h>

// HeteroRGCNLayer — round 8: bf16 Wh + block-range fusion for stage overlap.
// Pipeline: memset(cnt+total) -> [count ∥ gemmA] -> offsets -> [scatter ∥ gemmB] -> pull.
// gemm accumulates f32, stores Wh as bf16 (RNE); pull gathers bf16, accumulates f32.
//
// ws: Wh[3][50000][128] bf16 (38.4MB) | cnt[150000] | total | offsets[150000]
//     | cursor[150000] | edge_src[1.8M]  => ~47.4MB

#define N_NODES 50000
#define E_EDGES 600000
#define D 128
#define NROWS (3 * N_NODES)

#define RT 64
#define KC 16
#define NT ((N_NODES + RT - 1) / RT)     // 782 tiles/segment
#define GB3 (3 * NT)                     // 2346 gemm blocks total
#define GA 1173                          // gemm blocks fused with count
#define CB ((3 * E_EDGES + 255) / 256)   // 7032 edge blocks

static const size_t WH_STRIDE = (size_t)N_NODES * D;          // bf16 elements per segment
static const size_t WH_BYTES  = 3ull * WH_STRIDE * 2ull;      // 38,400,000
static const size_t OFF_CNT   = WH_BYTES;
static const size_t OFF_TOT   = OFF_CNT + 600000ull;
static const size_t OFF_OFFS  = OFF_TOT + 64ull;
static const size_t OFF_CUR   = OFF_OFFS + 600000ull;
static const size_t OFF_ESRC  = OFF_CUR + 600000ull;

__device__ __forceinline__ unsigned short f2bf(float x) {   // RNE f32->bf16
    unsigned u = __float_as_uint(x);
    unsigned r = u + 0x7FFFu + ((u >> 16) & 1u);
    return (unsigned short)(r >> 16);
}

// ---- GEMM block body (shared by both fused kernels). Wh[seg][i][o] bf16. ----
__device__ __forceinline__ void gemm_block(
    int gb,
    const float* __restrict__ feat_u, const float* __restrict__ feat_v,
    const float* __restrict__ W_uu, const float* __restrict__ b_uu,
    const float* __restrict__ W_vu, const float* __restrict__ b_vu,
    const float* __restrict__ W_uv, const float* __restrict__ b_uv,
    unsigned short* __restrict__ Wh)
{
    __shared__ float As[KC][RT];      // 4KB
    __shared__ float Bs[KC][132];     // 8.45KB

    const int seg  = gb / NT;
    const int tile = gb - seg * NT;
    const float* feat = (seg == 1) ? feat_v : feat_u;
    const float* W    = (seg == 0) ? W_uu : ((seg == 1) ? W_vu : W_uv);
    const float* bb   = (seg == 0) ? b_uu : ((seg == 1) ? b_vu : b_uv);
    unsigned short* WhS = Wh + (size_t)seg * WH_STRIDE;

    const int t  = threadIdx.x;
    const int tx = t & 15;
    const int ty = t >> 4;
    const int row0 = tile * RT;

    const int ar = t >> 2;
    const int ak = (t & 3) * 4;
    int grow = row0 + ar; if (grow > N_NODES - 1) grow = N_NODES - 1;
    const int wcol = t & 127;
    const int wkh  = (t >> 7) * 8;

    float acc[4][8];
#pragma unroll
    for (int r = 0; r < 4; ++r)
#pragma unroll
        for (int c = 0; c < 8; ++c) acc[r][c] = 0.0f;

    for (int kc = 0; kc < D; kc += KC) {
        {
            const float4 v = *(const float4*)&feat[(size_t)grow * D + kc + ak];
            As[ak + 0][ar] = v.x; As[ak + 1][ar] = v.y;
            As[ak + 2][ar] = v.z; As[ak + 3][ar] = v.w;
        }
        {
            const float4 v0 = *(const float4*)&W[(size_t)wcol * D + kc + wkh + 0];
            const float4 v1 = *(const float4*)&W[(size_t)wcol * D + kc + wkh + 4];
            Bs[wkh + 0][wcol] = v0.x; Bs[wkh + 1][wcol] = v0.y;
            Bs[wkh + 2][wcol] = v0.z; Bs[wkh + 3][wcol] = v0.w;
            Bs[wkh + 4][wcol] = v1.x; Bs[wkh + 5][wcol] = v1.y;
            Bs[wkh + 6][wcol] = v1.z; Bs[wkh + 7][wcol] = v1.w;
        }
        __syncthreads();

#pragma unroll
        for (int kk = 0; kk < KC; ++kk) {
            const float4 av = *(const float4*)&As[kk][ty * 4];
            const float4 b0 = *(const float4*)&Bs[kk][tx * 8];
            const float4 b1 = *(const float4*)&Bs[kk][tx * 8 + 4];
            const float ae[4] = {av.x, av.y, av.z, av.w};
            const float be[8] = {b0.x, b0.y, b0.z, b0.w, b1.x, b1.y, b1.z, b1.w};
#pragma unroll
            for (int r = 0; r < 4; ++r)
#pragma unroll
                for (int c = 0; c < 8; ++c)
                    acc[r][c] += ae[r] * be[c];
        }
        __syncthreads();
    }

    float bv[8];
    {
        const float4 b0 = *(const float4*)&bb[tx * 8];
        const float4 b1 = *(const float4*)&bb[tx * 8 + 4];
        bv[0] = b0.x; bv[1] = b0.y; bv[2] = b0.z; bv[3] = b0.w;
        bv[4] = b1.x; bv[5] = b1.y; bv[6] = b1.z; bv[7] = b1.w;
    }
#pragma unroll
    for (int r = 0; r < 4; ++r) {
        const int row = row0 + ty * 4 + r;
        if (row < N_NODES) {
            uint4 w;
            unsigned* wp = (unsigned*)&w;
#pragma unroll
            for (int j = 0; j < 4; ++j) {
                const unsigned lo = f2bf(acc[r][2 * j + 0] + bv[2 * j + 0]);
                const unsigned hi = f2bf(acc[r][2 * j + 1] + bv[2 * j + 1]);
                wp[j] = lo | (hi << 16);
            }
            *(uint4*)&WhS[(size_t)row * D + tx * 8] = w;   // 16B store
        }
    }
}

// ---- K2: count (blocks [0,CB)) ∥ gemm part A (blocks [CB, CB+GA)) ----
__global__ __launch_bounds__(256) void count_gemm_kernel(
    const int* __restrict__ d0, const int* __restrict__ d1, const int* __restrict__ d2,
    int* __restrict__ cnt,
    const float* __restrict__ feat_u, const float* __restrict__ feat_v,
    const float* __restrict__ W_uu, const float* __restrict__ b_uu,
    const float* __restrict__ W_vu, const float* __restrict__ b_vu,
    const float* __restrict__ W_uv, const float* __restrict__ b_uv,
    unsigned short* __restrict__ Wh)
{
    const int bx = blockIdx.x;
    if (bx < CB) {
        const int g = bx * 256 + threadIdx.x;
        if (g < 3 * E_EDGES) {
            int seg, e;
            if (g < E_EDGES)          { seg = 0; e = g; }
            else if (g < 2 * E_EDGES) { seg = 1; e = g - E_EDGES; }
            else                      { seg = 2; e = g - 2 * E_EDGES; }
            const int* dp = (seg == 0) ? d0 : ((seg == 1) ? d1 : d2);
            atomicAdd(&cnt[seg * N_NODES + dp[e]], 1);
        }
        return;
    }
    gemm_block(bx - CB, feat_u, feat_v, W_uu, b_uu, W_vu, b_vu, W_uv, b_uv, Wh);
}

// Unordered CSR offsets: wave shfl prefix + one atomicAdd per wave.
__global__ __launch_bounds__(256) void offsets_kernel(
    const int* __restrict__ cnt, int* __restrict__ offsets,
    int* __restrict__ cursor, int* __restrict__ total)
{
    const int g = blockIdx.x * 256 + threadIdx.x;
    const int lane = threadIdx.x & 63;
    const int c = (g < NROWS) ? cnt[g] : 0;
    int x = c;
#pragma unroll
    for (int off = 1; off < 64; off <<= 1) {
        int v = __shfl_up(x, off, 64);
        if (lane >= off) x += v;
    }
    const int wtot = __shfl(x, 63, 64);
    int base = 0;
    if (lane == 0) base = atomicAdd(total, wtot);
    base = __shfl(base, 0, 64);
    const int o = base + x - c;
    if (g < NROWS) { offsets[g] = o; cursor[g] = o; }
}

// ---- K4: scatter (blocks [0,CB)) ∥ gemm part B (blocks [CB, CB+GB3-GA)) ----
__global__ __launch_bounds__(256) void scatter_gemm_kernel(
    const int* __restrict__ s0, const int* __restrict__ d0,
    const int* __restrict__ s1, const int* __restrict__ d1,
    const int* __restrict__ s2, const int* __restrict__ d2,
    int* __restrict__ cursor, int* __restrict__ edge_src,
    const float* __restrict__ feat_u, const float* __restrict__ feat_v,
    const float* __restrict__ W_uu, const float* __restrict__ b_uu,
    const float* __restrict__ W_vu, const float* __restrict__ b_vu,
    const float* __restrict__ W_uv, const float* __restrict__ b_uv,
    unsigned short* __restrict__ Wh)
{
    const int bx = blockIdx.x;
    if (bx < CB) {
        const int g = bx * 256 + threadIdx.x;
        if (g < 3 * E_EDGES) {
            int seg, e;
            if (g < E_EDGES)          { seg = 0; e = g; }
            else if (g < 2 * E_EDGES) { seg = 1; e = g - E_EDGES; }
            else                      { seg = 2; e = g - 2 * E_EDGES; }
            const int* sp = (seg == 0) ? s0 : ((seg == 1) ? s1 : s2);
            const int* dp = (seg == 0) ? d0 : ((seg == 1) ? d1 : d2);
            const int pos = atomicAdd(&cursor[seg * N_NODES + dp[e]], 1);
            edge_src[pos] = sp[e];
        }
        return;
    }
    gemm_block(GA + (bx - CB), feat_u, feat_v, W_uu, b_uu, W_vu, b_vu, W_uv, b_uv, Wh);
}

// ---- bf16 segment-mean gather (f32 accumulate) ----
__device__ __forceinline__ float4 seg_mean(
    const unsigned short* __restrict__ tab, const int* __restrict__ edge_src,
    int start, int deg, int lane)
{
    float4 acc = make_float4(0.f, 0.f, 0.f, 0.f);
    for (int base = 0; base < deg; base += 32) {
        int id = 0;
        if (base + lane < deg) id = edge_src[start + base + lane];
        const int m = (deg - base < 32) ? (deg - base) : 32;
        int e = 0;
        for (; e + 1 < m; e += 2) {
            const int sA = __shfl(id, e, 32);
            const int sB = __shfl(id, e + 1, 32);
            const uint2 pA = *(const uint2*)&tab[(size_t)sA * D + lane * 4];
            const uint2 pB = *(const uint2*)&tab[(size_t)sB * D + lane * 4];
            acc.x += __uint_as_float(pA.x << 16);
            acc.y += __uint_as_float(pA.x & 0xFFFF0000u);
            acc.z += __uint_as_float(pA.y << 16);
            acc.w += __uint_as_float(pA.y & 0xFFFF0000u);
            acc.x += __uint_as_float(pB.x << 16);
            acc.y += __uint_as_float(pB.x & 0xFFFF0000u);
            acc.z += __uint_as_float(pB.y << 16);
            acc.w += __uint_as_float(pB.y & 0xFFFF0000u);
        }
        if (e < m) {
            const int sA = __shfl(id, e, 32);
            const uint2 pA = *(const uint2*)&tab[(size_t)sA * D + lane * 4];
            acc.x += __uint_as_float(pA.x << 16);
            acc.y += __uint_as_float(pA.x & 0xFFFF0000u);
            acc.z += __uint_as_float(pA.y << 16);
            acc.w += __uint_as_float(pA.y & 0xFFFF0000u);
        }
    }
    if (deg > 0) {
        const float inv = 1.0f / (float)deg;
        acc.x *= inv; acc.y *= inv; acc.z *= inv; acc.w *= inv;
    }
    return acc;
}

__global__ __launch_bounds__(256) void pull_kernel(
    const unsigned short* __restrict__ Wh_uu, const unsigned short* __restrict__ Wh_vu,
    const unsigned short* __restrict__ Wh_uv,
    const int* __restrict__ offsets, const int* __restrict__ cnt,
    const int* __restrict__ edge_src, float* __restrict__ out)
{
    const int lane = threadIdx.x & 31;
    const int grp  = threadIdx.x >> 5;
    const int row  = blockIdx.x * 8 + grp;
    if (row < N_NODES) {
        const float4 a = seg_mean(Wh_uu, edge_src, offsets[row], cnt[row], lane);
        const float4 b = seg_mean(Wh_vu, edge_src,
                                  offsets[N_NODES + row], cnt[N_NODES + row], lane);
        const float4 r = make_float4(a.x + b.x, a.y + b.y, a.z + b.z, a.w + b.w);
        *(float4*)&out[(size_t)row * D + lane * 4] = r;
    } else {
        const int rr = row - N_NODES;
        const float4 a = seg_mean(Wh_uv, edge_src,
                                  offsets[2 * N_NODES + rr], cnt[2 * N_NODES + rr], lane);
        *(float4*)&out[((size_t)N_NODES + rr) * D + lane * 4] = a;
    }
}

extern "C" void kernel_launch(void* const* d_in, const int* in_sizes, int n_in,
                              void* d_out, int out_size, void* d_ws, size_t ws_size,
                              hipStream_t stream)
{
    const float* feat_u = (const float*)d_in[0];
    const float* feat_v = (const float*)d_in[1];
    const float* W_uu   = (const float*)d_in[2];
    const float* b_uu   = (const float*)d_in[3];
    const float* W_uv   = (const float*)d_in[4];
    const float* b_uv   = (const float*)d_in[5];
    const float* W_vu   = (const float*)d_in[6];
    const float* b_vu   = (const float*)d_in[7];
    const int* src_uu = (const int*)d_in[8];
    const int* dst_uu = (const int*)d_in[9];
    const int* src_uv = (const int*)d_in[10];
    const int* dst_uv = (const int*)d_in[11];
    const int* src_vu = (const int*)d_in[12];
    const int* dst_vu = (const int*)d_in[13];

    char* ws = (char*)d_ws;
    unsigned short* Wh = (unsigned short*)ws;
    int* cnt     = (int*)(ws + OFF_CNT);
    int* total   = (int*)(ws + OFF_TOT);
    int* offsets = (int*)(ws + OFF_OFFS);
    int* cursor  = (int*)(ws + OFF_CUR);
    int* edge_src= (int*)(ws + OFF_ESRC);
    float* out = (float*)d_out;

    hipMemsetAsync(cnt, 0, 600064ull, stream);   // cnt + total

    // K2: count ∥ gemm part A
    count_gemm_kernel<<<CB + GA, 256, 0, stream>>>(
        dst_uu, dst_vu, dst_uv, cnt,
        feat_u, feat_v, W_uu, b_uu, W_vu, b_vu, W_uv, b_uv, Wh);

    offsets_kernel<<<(NROWS + 255) / 256, 256, 0, stream>>>(cnt, offsets, cursor, total);

    // K4: scatter ∥ gemm part B
    scatter_gemm_kernel<<<CB + (GB3 - GA), 256, 0, stream>>>(
        src_uu, dst_uu, src_vu, dst_vu, src_uv, dst_uv,
        cursor, edge_src,
        feat_u, feat_v, W_uu, b_uu, W_vu, b_vu, W_uv, b_uv, Wh);

    pull_kernel<<<(2 * N_NODES) / 8, 256, 0, stream>>>(
        Wh + 0 * WH_STRIDE, Wh + 1 * WH_STRIDE, Wh + 2 * WH_STRIDE,
        offsets, cnt, edge_src, out);
}